// Round 17
// baseline (460.506 us; speedup 1.0000x reference)
//
#include <hip/hip_runtime.h>
#include <hip/hip_bf16.h>

typedef __bf16 bf16x8 __attribute__((ext_vector_type(8)));
typedef __bf16 bf16x4 __attribute__((ext_vector_type(4)));
typedef float  f32x4  __attribute__((ext_vector_type(4)));

#define LAYERS 6
#define BATCH  4
#define SEQ    1024
#define DMODEL 256
#define NHEAD  8
#define DHEAD  32
#define FFDIM  128
#define ROWS   (BATCH*SEQ)          // 4096
#define QKVN   (3*DMODEL)           // 768
#define QSCALE 0.2550348616f        // (1/sqrt(32)) * log2(e): folded into q so p = exp2(d)
#define PFBLKS (ROWS/16)            // 256 pf blocks
#define AWBLKS (SEQ/16*NHEAD*BATCH) // 2048 aw blocks

static __device__ __forceinline__ bf16x8 ldg8(const __bf16* p) {
  return *reinterpret_cast<const bf16x8*>(p);
}
#define MFMA16(a, b, c) __builtin_amdgcn_mfma_f32_16x16x32_bf16((a), (b), (c), 0, 0, 0)

// ---------------- LDS-tiled weight transpose: in fp32 [l][R][C] -> out bf16 [l][C][R]
__global__ __launch_bounds__(256) void k_prepT(const float* __restrict__ in,
                                               __bf16* __restrict__ out,
                                               int R, int C) {
  __shared__ __bf16 T[64][72];
  int l = blockIdx.z, r0 = blockIdx.y * 64, c0 = blockIdx.x * 64;
  const float* src = in + ((size_t)l * R + r0) * C + c0;
  int tr = threadIdx.x >> 6, tc = threadIdx.x & 63;
  #pragma unroll 4
  for (int it = 0; it < 16; ++it) {
    int r = it * 4 + tr;
    T[r][tc] = (__bf16)src[(size_t)r * C + tc];
  }
  __syncthreads();
  __bf16* dst = out + ((size_t)l * C + c0) * R + r0;
  #pragma unroll 4
  for (int it = 0; it < 16; ++it) {
    int c = it * 4 + tr;
    dst[(size_t)c * R + tc] = T[tc][c];
  }
}

// ---------------- standalone layernorm (layer 0 LN1 only) ----------------
__global__ __launch_bounds__(64) void k_ln(const float* __restrict__ x,
                                           const float* __restrict__ w,
                                           const float* __restrict__ b,
                                           __bf16* __restrict__ out) {
  int row = blockIdx.x, l = threadIdx.x;
  const float* xr = x + (size_t)row * DMODEL;
  float v[4];
  #pragma unroll
  for (int j = 0; j < 4; ++j) v[j] = xr[l + 64 * j];
  float s = v[0] + v[1] + v[2] + v[3];
  #pragma unroll
  for (int off = 32; off >= 1; off >>= 1) s += __shfl_xor(s, off);
  float mean = s * (1.0f / DMODEL);
  float sq = 0.f;
  #pragma unroll
  for (int j = 0; j < 4; ++j) { v[j] -= mean; sq += v[j] * v[j]; }
  #pragma unroll
  for (int off = 32; off >= 1; off >>= 1) sq += __shfl_xor(sq, off);
  float rstd = rsqrtf(sq * (1.0f / DMODEL) + 1e-5f);
  __bf16* orow = out + (size_t)row * DMODEL;
  #pragma unroll
  for (int j = 0; j < 4; ++j) {
    int c = l + 64 * j;
    orow[c] = (__bf16)(v[j] * rstd * w[c] + b[c]);
  }
}

// ---------------- QKV GEMM + scatter epilogue (layer 0 only) ----------------
__global__ __launch_bounds__(256) void k_qkv(const __bf16* __restrict__ xn,
                                             const __bf16* __restrict__ Bt,
                                             __bf16* __restrict__ qb,
                                             __bf16* __restrict__ kt,
                                             __bf16* __restrict__ vt) {
  int w = threadIdx.x >> 6, l = threadIdx.x & 63, lr = l & 15, lg = l >> 4;
  int m0 = blockIdx.x * 64 + w * 16;
  int n0 = blockIdx.y * 64;
  f32x4 acc[4] = {};
  const __bf16* ap = xn + (size_t)(m0 + lr) * DMODEL + 8 * lg;
  const __bf16* bp = Bt + (size_t)(n0 + lr) * DMODEL + 8 * lg;
  for (int kc = 0; kc < DMODEL; kc += 32) {
    bf16x8 a = ldg8(ap + kc);
    #pragma unroll
    for (int t = 0; t < 4; ++t) {
      bf16x8 b = ldg8(bp + (size_t)t * 16 * DMODEL + kc);
      acc[t] = MFMA16(a, b, acc[t]);
    }
  }
  int row = m0 + lg * 4;
  if (n0 < DMODEL) {
    #pragma unroll
    for (int t = 0; t < 4; ++t) {
      int col = n0 + t * 16 + lr;
      #pragma unroll
      for (int r = 0; r < 4; ++r)
        qb[(size_t)(row + r) * DMODEL + col] = (__bf16)(acc[t][r] * QSCALE);
    }
  } else if (n0 < 2 * DMODEL) {
    int b_ = row >> 10, s = row & (SEQ - 1);
    #pragma unroll
    for (int t = 0; t < 4; ++t) {
      int hdh = n0 - DMODEL + t * 16 + lr;
      int h = hdh >> 5, dh = hdh & 31;
      size_t base = ((size_t)(b_ * NHEAD + h) * SEQ + s) * DHEAD + dh;
      #pragma unroll
      for (int r = 0; r < 4; ++r) kt[base + (size_t)r * DHEAD] = (__bf16)acc[t][r];
    }
  } else {
    int b_ = row >> 10, s = row & (SEQ - 1);
    #pragma unroll
    for (int t = 0; t < 4; ++t) {
      int hdh = n0 - 2 * DMODEL + t * 16 + lr;
      int h = hdh >> 5, dh = hdh & 31;
      bf16x4 v4;
      #pragma unroll
      for (int r = 0; r < 4; ++r) v4[r] = (__bf16)acc[t][r];
      *reinterpret_cast<bf16x4*>(vt + ((size_t)(b_ * NHEAD + h) * DHEAD + dh) * SEQ + s) = v4;
    }
  }
}

// ---------------- attention CORE: single-pass, no aw stores, writes O + rinv --------
__global__ __launch_bounds__(512, 6) void k_attn(const __bf16* __restrict__ qb,
                                                 const __bf16* __restrict__ kt,
                                                 const __bf16* __restrict__ vt,
                                                 __bf16* __restrict__ ob,
                                                 float* __restrict__ rb) {
  __shared__ __bf16 P[8][2][16][40];
  __shared__ float  Ssum[8][16];
  __shared__ float  OS[8][16][34];
  int bid = blockIdx.x;
  int swz = (bid & 7) * 256 + (bid >> 3);      // 2048 = 8 XCD chunks of 256
  int qblk = swz & 63, h = (swz >> 6) & 7, b = swz >> 9;
  int w = threadIdx.x >> 6, l = threadIdx.x & 63, lr = l & 15, lg = l >> 4;
  int q0 = qblk * 16;
  bf16x8 qf = ldg8(qb + ((size_t)(b * SEQ) + q0 + lr) * DMODEL + h * DHEAD + 8 * lg);
  const __bf16* ktb = kt + (size_t)(b * NHEAD + h) * SEQ * DHEAD + 8 * lg;
  const __bf16* vtb = vt + (size_t)(b * NHEAD + h) * DHEAD * SEQ;
  f32x4 z = {};
  int kbeg = w * 128;

  float s4[4] = {0.f, 0.f, 0.f, 0.f};

#define QK_TILE(KC, BUF)                                                          \
  {                                                                               \
    _Pragma("unroll")                                                             \
    for (int half = 0; half < 2; ++half) {                                        \
      int k0 = (KC) + half * 16;                                                  \
      bf16x8 kf = ldg8(ktb + (size_t)(k0 + lr) * DHEAD);                          \
      f32x4 d = MFMA16(qf, kf, z);                                                \
      _Pragma("unroll")                                                           \
      for (int r = 0; r < 4; ++r) {                                               \
        float pv = exp2f(d[r]);                                                   \
        s4[r] += pv;                                                              \
        P[w][BUF][lg * 4 + r][half * 16 + lr] = (__bf16)pv;                       \
      }                                                                           \
    }                                                                             \
  }

  f32x4 accO[2] = {};
  QK_TILE(kbeg, 0)
  #pragma unroll
  for (int j = 1; j < 4; ++j) {
    int kc = kbeg + j * 32;
    bf16x8 pf  = *reinterpret_cast<const bf16x8*>(&P[w][(j - 1) & 1][lr][8 * lg]);
    bf16x8 vf0 = ldg8(vtb + (size_t)lr * SEQ + (kc - 32) + 8 * lg);
    bf16x8 vf1 = ldg8(vtb + (size_t)(16 + lr) * SEQ + (kc - 32) + 8 * lg);
    QK_TILE(kc, j & 1)
    accO[0] = MFMA16(pf, vf0, accO[0]);
    accO[1] = MFMA16(pf, vf1, accO[1]);
  }
  {                                      // last PV tile (j=3 -> buf 1)
    bf16x8 pf  = *reinterpret_cast<const bf16x8*>(&P[w][1][lr][8 * lg]);
    bf16x8 vf0 = ldg8(vtb + (size_t)lr * SEQ + (kbeg + 96) + 8 * lg);
    bf16x8 vf1 = ldg8(vtb + (size_t)(16 + lr) * SEQ + (kbeg + 96) + 8 * lg);
    accO[0] = MFMA16(pf, vf0, accO[0]);
    accO[1] = MFMA16(pf, vf1, accO[1]);
  }
#undef QK_TILE

  #pragma unroll
  for (int off = 1; off < 16; off <<= 1) {
    #pragma unroll
    for (int r = 0; r < 4; ++r) s4[r] += __shfl_xor(s4[r], off);
  }
  if (lr == 0) {
    #pragma unroll
    for (int r = 0; r < 4; ++r) Ssum[w][lg * 4 + r] = s4[r];
  }
  __syncthreads();
  float rinv[4];
  #pragma unroll
  for (int r = 0; r < 4; ++r) {
    int row = lg * 4 + r;
    float s = Ssum[0][row] + Ssum[1][row] + Ssum[2][row] + Ssum[3][row]
            + Ssum[4][row] + Ssum[5][row] + Ssum[6][row] + Ssum[7][row];
    rinv[r] = 1.0f / s;
  }
  if (w == 0 && l < 16) {                // rinv -> global for the aw-stream blocks
    float s = 0.f;
    #pragma unroll
    for (int ww = 0; ww < 8; ++ww) s += Ssum[ww][l];
    rb[((size_t)(b * SEQ) + q0 + l) * NHEAD + h] = 1.0f / s;
  }

  #pragma unroll
  for (int t = 0; t < 2; ++t)
    #pragma unroll
    for (int r = 0; r < 4; ++r) OS[w][lg * 4 + r][t * 16 + lr] = accO[t][r] * rinv[r];
  __syncthreads();
  int row = threadIdx.x >> 5, col = threadIdx.x & 31;
  float o = 0.f;
  #pragma unroll
  for (int ww = 0; ww < 8; ++ww) o += OS[ww][row][col];
  ob[((size_t)(b * SEQ) + q0 + row) * DMODEL + h * DHEAD + col] = (__bf16)o;
}

// ================= fat kernel: pf blocks [0,256) + aw-stream blocks [256,2304) ========
// pf: out-proj + residual + LN2 + FFN1 + in-wave GEGLU + FFN2 + residual + LN1(next)
//     + QKV(next, ping-pong). aw: recompute QK, scale by rinv, nt-stream to d_out.
// The two halves are independent -> aw writes drain under the latency-bound pf chain.
template <int LAST>
__global__ __launch_bounds__(512) void k_pfaw(const __bf16* __restrict__ ob,
                                              const __bf16* __restrict__ qbr,
                                              const __bf16* __restrict__ ktr,
                                              const float* __restrict__ rb,
                                              float* __restrict__ aw,
                                              const __bf16* __restrict__ woutT,
                                              const float* __restrict__ xres,
                                              const float* __restrict__ ln2w,
                                              const float* __restrict__ ln2b,
                                              const __bf16* __restrict__ w1t,
                                              const float* __restrict__ b1,
                                              const __bf16* __restrict__ w2t,
                                              const float* __restrict__ b2,
                                              float* __restrict__ x32out,
                                              const float* __restrict__ lnw_n,
                                              const float* __restrict__ lnb_n,
                                              const __bf16* __restrict__ wqkvT_n,
                                              __bf16* __restrict__ qb_n,
                                              __bf16* __restrict__ kt_n,
                                              __bf16* __restrict__ vt_n,
                                              float* __restrict__ xout) {
  __shared__ char smem[17152 + 8448 + 4352];   // pf: xs | XN | HT ; aw: ST (16KB)
  int w = threadIdx.x >> 6, l = threadIdx.x & 63, lr = l & 15, lg = l >> 4;

  if (blockIdx.x >= PFBLKS) {
    // ======== aw-stream block: 16 q-rows x 1024 keys, wave w -> keys [w*128,+128) ======
    float (*ST)[16][32] = reinterpret_cast<float(*)[16][32]>(smem);
    int bid = blockIdx.x - PFBLKS;
    int swz = (bid & 7) * 256 + (bid >> 3);    // XCD-chunked
    int qblk = swz & 63, h = (swz >> 6) & 7, b = swz >> 9;
    int q0 = qblk * 16;
    bf16x8 qf = ldg8(qbr + ((size_t)(b * SEQ) + q0 + lr) * DMODEL + h * DHEAD + 8 * lg);
    const __bf16* ktb = ktr + (size_t)(b * NHEAD + h) * SEQ * DHEAD + 8 * lg;
    float rv[4];
    #pragma unroll
    for (int r = 0; r < 4; ++r)
      rv[r] = rb[((size_t)(b * SEQ) + q0 + lg * 4 + r) * NHEAD + h];
    float* awb = aw + ((size_t)(b * NHEAD + h) * SEQ) * SEQ;
    f32x4 z = {};
    int kbeg = w * 128;
    #pragma unroll
    for (int t0 = 0; t0 < 8; ++t0) {
      bf16x8 kf = ldg8(ktb + (size_t)(kbeg + t0 * 16 + lr) * DHEAD);
      f32x4 d = MFMA16(qf, kf, z);
      #pragma unroll
      for (int r = 0; r < 4; ++r)
        ST[w][lg * 4 + r][(t0 & 1) * 16 + lr] = exp2f(d[r]) * rv[r];
      if (t0 & 1) {                            // flush 32 keys (same-wave LDS: in-order)
        int frow = l >> 3, fcol = (l & 7) * 4;
        int kc = kbeg + (t0 - 1) * 16;
        f32x4 v0 = *reinterpret_cast<const f32x4*>(&ST[w][frow][fcol]);
        f32x4 v1 = *reinterpret_cast<const f32x4*>(&ST[w][frow + 8][fcol]);
        __builtin_nontemporal_store(v0, reinterpret_cast<f32x4*>(
            &awb[(size_t)(q0 + frow) * SEQ + kc + fcol]));
        __builtin_nontemporal_store(v1, reinterpret_cast<f32x4*>(
            &awb[(size_t)(q0 + frow + 8) * SEQ + kc + fcol]));
      }
    }
    return;
  }

  // ======== pf block ========
  float  (*xs)[268] = reinterpret_cast<float(*)[268]>(smem);
  __bf16 (*XN)[264] = reinterpret_cast<__bf16(*)[264]>(smem + 17152);
  __bf16 (*HT)[136] = reinterpret_cast<__bf16(*)[136]>(smem + 17152 + 8448);
  int m0 = blockIdx.x * 16;
  // ---- out-proj GEMM, wave w -> 32 cols
  {
    int n0 = w * 32;
    f32x4 acc[2] = {};
    const __bf16* ap = ob + (size_t)(m0 + lr) * DMODEL + 8 * lg;
    const __bf16* bp = woutT + (size_t)(n0 + lr) * DMODEL + 8 * lg;
    for (int kc = 0; kc < DMODEL; kc += 32) {
      bf16x8 a = ldg8(ap + kc);
      #pragma unroll
      for (int t = 0; t < 2; ++t)
        acc[t] = MFMA16(a, ldg8(bp + (size_t)t * 16 * DMODEL + kc), acc[t]);
    }
    #pragma unroll
    for (int t = 0; t < 2; ++t) {
      int col = n0 + t * 16 + lr;
      #pragma unroll
      for (int r = 0; r < 4; ++r) {
        int row = lg * 4 + r;
        xs[row][col] = acc[t][r] + xres[(size_t)(m0 + row) * DMODEL + col];
      }
    }
  }
  __syncthreads();
  // ---- LN2 -> XN; wave w handles rows w*2..+2
  #pragma unroll
  for (int rr = 0; rr < 2; ++rr) {
    int row = w * 2 + rr;
    f32x4 v = *reinterpret_cast<const f32x4*>(&xs[row][4 * l]);
    float s = v[0] + v[1] + v[2] + v[3];
    #pragma unroll
    for (int off = 32; off >= 1; off >>= 1) s += __shfl_xor(s, off);
    float mean = s * (1.0f / DMODEL);
    float sq = 0.f;
    f32x4 c;
    #pragma unroll
    for (int j = 0; j < 4; ++j) { c[j] = v[j] - mean; sq += c[j] * c[j]; }
    #pragma unroll
    for (int off = 32; off >= 1; off >>= 1) sq += __shfl_xor(sq, off);
    float rstd = rsqrtf(sq * (1.0f / DMODEL) + 1e-5f);
    f32x4 lwv = *reinterpret_cast<const f32x4*>(&ln2w[4 * l]);
    f32x4 lbv = *reinterpret_cast<const f32x4*>(&ln2b[4 * l]);
    bf16x4 o4;
    #pragma unroll
    for (int j = 0; j < 4; ++j) o4[j] = (__bf16)(c[j] * rstd * lwv[j] + lbv[j]);
    *reinterpret_cast<bf16x4*>(&XN[row][4 * l]) = o4;
  }
  __syncthreads();
  // ---- FFN1 + in-wave GEGLU: wave w -> a-cols [w*16,+16), g-cols [128+w*16,+16)
  {
    f32x4 acc1[2] = {};
    const __bf16* bpa = w1t + (size_t)(w * 16 + lr) * DMODEL + 8 * lg;
    const __bf16* bpg = w1t + (size_t)(128 + w * 16 + lr) * DMODEL + 8 * lg;
    for (int kc = 0; kc < DMODEL; kc += 32) {
      bf16x8 a = *reinterpret_cast<const bf16x8*>(&XN[lr][kc + 8 * lg]);
      acc1[0] = MFMA16(a, ldg8(bpa + kc), acc1[0]);
      acc1[1] = MFMA16(a, ldg8(bpg + kc), acc1[1]);
    }
    int fc = w * 16 + lr;
    #pragma unroll
    for (int r = 0; r < 4; ++r) {
      float a1 = acc1[0][r] + b1[fc];
      float g  = acc1[1][r] + b1[fc + 128];
      float ge = 0.5f * g * (1.0f + erff(g * 0.70710678118654752f));
      HT[lg * 4 + r][fc] = (__bf16)(a1 * ge);
    }
  }
  __syncthreads();
  // ---- FFN2: wave w -> 32 cols, K = 128
  {
    int n0 = w * 32;
    f32x4 acc2[2] = {};
    const __bf16* bp = w2t + (size_t)(n0 + lr) * FFDIM + 8 * lg;
    for (int kc = 0; kc < FFDIM; kc += 32) {
      bf16x8 a2 = *reinterpret_cast<const bf16x8*>(&HT[lr][kc + 8 * lg]);
      #pragma unroll
      for (int t = 0; t < 2; ++t)
        acc2[t] = MFMA16(a2, ldg8(bp + (size_t)t * 16 * FFDIM + kc), acc2[t]);
    }
    #pragma unroll
    for (int t = 0; t < 2; ++t) {
      int col = n0 + t * 16 + lr;
      #pragma unroll
      for (int r = 0; r < 4; ++r) {
        int row = lg * 4 + r;
        xs[row][col] = acc2[t][r] + b2[col] + xs[row][col];
      }
    }
  }
  __syncthreads();
  // ---- final: residual out + LN1(next) -> XN, or fp32 output
  #pragma unroll
  for (int rr = 0; rr < 2; ++rr) {
    int row = w * 2 + rr;
    f32x4 v = *reinterpret_cast<const f32x4*>(&xs[row][4 * l]);
    if (LAST) {
      *reinterpret_cast<f32x4*>(&xout[(size_t)(m0 + row) * DMODEL + 4 * l]) = v;
    } else {
      float s = v[0] + v[1] + v[2] + v[3];
      #pragma unroll
      for (int off = 32; off >= 1; off >>= 1) s += __shfl_xor(s, off);
      float mean = s * (1.0f / DMODEL);
      float sq = 0.f;
      f32x4 c;
      #pragma unroll
      for (int j = 0; j < 4; ++j) { c[j] = v[j] - mean; sq += c[j] * c[j]; }
      #pragma unroll
      for (int off = 32; off >= 1; off >>= 1) sq += __shfl_xor(sq, off);
      float rstd = rsqrtf(sq * (1.0f / DMODEL) + 1e-5f);
      *reinterpret_cast<f32x4*>(&x32out[(size_t)(m0 + row) * DMODEL + 4 * l]) = v;
      f32x4 lwv = *reinterpret_cast<const f32x4*>(&lnw_n[4 * l]);
      f32x4 lbv = *reinterpret_cast<const f32x4*>(&lnb_n[4 * l]);
      bf16x4 o4;
      #pragma unroll
      for (int j = 0; j < 4; ++j) o4[j] = (__bf16)(c[j] * rstd * lwv[j] + lbv[j]);
      *reinterpret_cast<bf16x4*>(&XN[row][4 * l]) = o4;
    }
  }
  if (!LAST) {
    __syncthreads();
    // ---- QKV(next): wave w -> 96 cols of 768; ping-pong outputs
    f32x4 acc[6] = {};
    {
      const __bf16* bp = wqkvT_n + (size_t)(w * 96 + lr) * DMODEL + 8 * lg;
      for (int kc = 0; kc < DMODEL; kc += 32) {
        bf16x8 a = *reinterpret_cast<const bf16x8*>(&XN[lr][kc + 8 * lg]);
        #pragma unroll
        for (int t = 0; t < 6; ++t)
          acc[t] = MFMA16(a, ldg8(bp + (size_t)t * 16 * DMODEL + kc), acc[t]);
      }
    }
    int row = m0 + lg * 4;
    int b_ = row >> 10, s = row & (SEQ - 1);
    #pragma unroll
    for (int t = 0; t < 6; ++t) {
      int col = w * 96 + t * 16 + lr;
      if (col < DMODEL) {                // Q (prescaled)
        #pragma unroll
        for (int r = 0; r < 4; ++r)
          qb_n[(size_t)(row + r) * DMODEL + col] = (__bf16)(acc[t][r] * QSCALE);
      } else if (col < 2 * DMODEL) {     // K
        int hdh = col - DMODEL;
        int h = hdh >> 5, dh = hdh & 31;
        size_t base = ((size_t)(b_ * NHEAD + h) * SEQ + s) * DHEAD + dh;
        #pragma unroll
        for (int r = 0; r < 4; ++r) kt_n[base + (size_t)r * DHEAD] = (__bf16)acc[t][r];
      } else {                           // V
        int hdh = col - 2 * DMODEL;
        int h = hdh >> 5, dh = hdh & 31;
        bf16x4 v4;
        #pragma unroll
        for (int r = 0; r < 4; ++r) v4[r] = (__bf16)acc[t][r];
        *reinterpret_cast<bf16x4*>(vt_n + ((size_t)(b_ * NHEAD + h) * DHEAD + dh) * SEQ + s) = v4;
      }
    }
  }
}

// ---------------- host ----------------
static inline size_t align256(size_t x) { return (x + 255) & ~(size_t)255; }

extern "C" void kernel_launch(void* const* d_in, const int* in_sizes, int n_in,
                              void* d_out, int out_size, void* d_ws, size_t ws_size,
                              hipStream_t stream) {
  const float* x_in = (const float*)d_in[0];
  const float* ln1w = (const float*)d_in[1];
  const float* ln1b = (const float*)d_in[2];
  const float* wqkv = (const float*)d_in[3];
  const float* wout = (const float*)d_in[4];
  const float* ln2w = (const float*)d_in[5];
  const float* ln2b = (const float*)d_in[6];
  const float* w1   = (const float*)d_in[7];
  const float* b1   = (const float*)d_in[8];
  const float* w2   = (const float*)d_in[9];
  const float* b2   = (const float*)d_in[10];
  float* out = (float*)d_out;

  char* p = (char*)d_ws;
  float*  x32   = (float*)p;  p += align256((size_t)ROWS * DMODEL * 4);
  __bf16* xn    = (__bf16*)p; p += align256((size_t)ROWS * DMODEL * 2);
  __bf16* qbA   = (__bf16*)p; p += align256((size_t)ROWS * DMODEL * 2);
  __bf16* ktA   = (__bf16*)p; p += align256((size_t)ROWS * DMODEL * 2);
  __bf16* vtA   = (__bf16*)p; p += align256((size_t)ROWS * DMODEL * 2);
  __bf16* qbB   = (__bf16*)p; p += align256((size_t)ROWS * DMODEL * 2);
  __bf16* ktB   = (__bf16*)p; p += align256((size_t)ROWS * DMODEL * 2);
  __bf16* vtB   = (__bf16*)p; p += align256((size_t)ROWS * DMODEL * 2);
  __bf16* ob    = (__bf16*)p; p += align256((size_t)ROWS * DMODEL * 2);
  float*  rb    = (float*)p;  p += align256((size_t)ROWS * NHEAD * 4);
  __bf16* wqkvT = (__bf16*)p; p += align256((size_t)LAYERS * DMODEL * QKVN * 2);
  __bf16* woutT = (__bf16*)p; p += align256((size_t)LAYERS * DMODEL * DMODEL * 2);
  __bf16* w1T   = (__bf16*)p; p += align256((size_t)LAYERS * DMODEL * 2 * FFDIM * 2);
  __bf16* w2T   = (__bf16*)p; p += align256((size_t)LAYERS * FFDIM * DMODEL * 2);

  k_prepT<<<dim3(QKVN / 64, DMODEL / 64, LAYERS), 256, 0, stream>>>(wqkv, wqkvT, DMODEL, QKVN);
  k_prepT<<<dim3(DMODEL / 64, DMODEL / 64, LAYERS), 256, 0, stream>>>(wout, woutT, DMODEL, DMODEL);
  k_prepT<<<dim3(2 * FFDIM / 64, DMODEL / 64, LAYERS), 256, 0, stream>>>(w1, w1T, DMODEL, 2 * FFDIM);
  k_prepT<<<dim3(DMODEL / 64, FFDIM / 64, LAYERS), 256, 0, stream>>>(w2, w2T, FFDIM, DMODEL);
  k_ln<<<ROWS, 64, 0, stream>>>(x_in, ln1w, ln1b, xn);
  k_qkv<<<dim3(ROWS / 64, QKVN / 64), 256, 0, stream>>>(xn, wqkvT, qbA, ktA, vtA);

  const size_t AW_LAYER = (size_t)BATCH * NHEAD * SEQ * SEQ;
  for (int i = 0; i < LAYERS; ++i) {
    float* aw_l = out + (size_t)ROWS * DMODEL + (size_t)i * AW_LAYER;
    const float* xres = (i == 0) ? x_in : x32;
    __bf16* qb_c = (i & 1) ? qbB : qbA;
    __bf16* kt_c = (i & 1) ? ktB : ktA;
    __bf16* vt_c = (i & 1) ? vtB : vtA;
    __bf16* qb_n = (i & 1) ? qbA : qbB;
    __bf16* kt_n = (i & 1) ? ktA : ktB;
    __bf16* vt_n = (i & 1) ? vtA : vtB;
    k_attn<<<AWBLKS, 512, 0, stream>>>(qb_c, kt_c, vt_c, ob, rb);
    if (i < LAYERS - 1) {
      k_pfaw<0><<<PFBLKS + AWBLKS, 512, 0, stream>>>(
          ob, qb_c, kt_c, rb, aw_l,
          woutT + (size_t)i * DMODEL * DMODEL, xres,
          ln2w + i * DMODEL, ln2b + i * DMODEL,
          w1T + (size_t)i * DMODEL * 2 * FFDIM, b1 + i * 2 * FFDIM,
          w2T + (size_t)i * FFDIM * DMODEL, b2 + i * DMODEL,
          x32, ln1w + (i + 1) * DMODEL, ln1b + (i + 1) * DMODEL,
          wqkvT + (size_t)(i + 1) * DMODEL * QKVN, qb_n, kt_n, vt_n, nullptr);
    } else {
      k_pfaw<1><<<PFBLKS + AWBLKS, 512, 0, stream>>>(
          ob, qb_c, kt_c, rb, aw_l,
          woutT + (size_t)i * DMODEL * DMODEL, xres,
          ln2w + i * DMODEL, ln2b + i * DMODEL,
          w1T + (size_t)i * DMODEL * 2 * FFDIM, b1 + i * 2 * FFDIM,
          w2T + (size_t)i * FFDIM * DMODEL, b2 + i * DMODEL,
          x32, nullptr, nullptr, nullptr, nullptr, nullptr, nullptr, out);
    }
  }
}

// Round 18
// 415.936 us; speedup vs baseline: 1.1072x; 1.1072x over previous
//
#include <hip/hip_runtime.h>
#include <hip/hip_bf16.h>

typedef __bf16 bf16x8 __attribute__((ext_vector_type(8)));
typedef __bf16 bf16x4 __attribute__((ext_vector_type(4)));
typedef float  f32x4  __attribute__((ext_vector_type(4)));

#define LAYERS 6
#define BATCH  4
#define SEQ    1024
#define DMODEL 256
#define NHEAD  8
#define DHEAD  32
#define FFDIM  128
#define ROWS   (BATCH*SEQ)          // 4096
#define QKVN   (3*DMODEL)           // 768
#define QSCALE 0.2550348616f        // (1/sqrt(32)) * log2(e): folded into q so p = exp2(d)

static __device__ __forceinline__ bf16x8 ldg8(const __bf16* p) {
  return *reinterpret_cast<const bf16x8*>(p);
}
#define MFMA16(a, b, c) __builtin_amdgcn_mfma_f32_16x16x32_bf16((a), (b), (c), 0, 0, 0)

// ---------------- merged weight transpose: all 4 matrices in ONE launch ----------------
// grid (88, 1, LAYERS): tiles 0-47 wqkv, 48-63 wout, 64-79 w1, 80-87 w2.
__global__ __launch_bounds__(256) void k_prepAll(const float* __restrict__ wqkv,
                                                 const float* __restrict__ wout,
                                                 const float* __restrict__ w1,
                                                 const float* __restrict__ w2,
                                                 __bf16* __restrict__ wqkvT,
                                                 __bf16* __restrict__ woutT,
                                                 __bf16* __restrict__ w1T,
                                                 __bf16* __restrict__ w2T) {
  __shared__ __bf16 T[64][72];
  int t = blockIdx.x, lay = blockIdx.z;
  const float* in; __bf16* out; int R, C, rblk, cblk;
  if (t < 48)      { in = wqkv; out = wqkvT; R = DMODEL; C = QKVN;     int u = t;      cblk = u % 12; rblk = u / 12; }
  else if (t < 64) { in = wout; out = woutT; R = DMODEL; C = DMODEL;   int u = t - 48; cblk = u % 4;  rblk = u / 4; }
  else if (t < 80) { in = w1;   out = w1T;   R = DMODEL; C = 2 * FFDIM;int u = t - 64; cblk = u % 4;  rblk = u / 4; }
  else             { in = w2;   out = w2T;   R = FFDIM;  C = DMODEL;   int u = t - 80; cblk = u % 4;  rblk = u / 4; }
  int r0 = rblk * 64, c0 = cblk * 64;
  const float* src = in + ((size_t)lay * R + r0) * C + c0;
  int tr = threadIdx.x >> 6, tc = threadIdx.x & 63;
  #pragma unroll 4
  for (int it = 0; it < 16; ++it) {
    int r = it * 4 + tr;
    T[r][tc] = (__bf16)src[(size_t)r * C + tc];
  }
  __syncthreads();
  __bf16* dst = out + ((size_t)lay * C + c0) * R + r0;
  #pragma unroll 4
  for (int it = 0; it < 16; ++it) {
    int c = it * 4 + tr;
    dst[(size_t)c * R + tc] = T[tc][c];
  }
}

// ---------------- QKV GEMM with FUSED LN1 (layer 0 only; reads x_in directly) ---------
// grid (ROWS/64, QKVN/64), 256 thr. Phase 1: LN of 64 rows -> LDS. Phase 2: GEMM.
__global__ __launch_bounds__(256) void k_qkv(const float* __restrict__ x,
                                             const float* __restrict__ lw,
                                             const float* __restrict__ lb,
                                             const __bf16* __restrict__ Bt,
                                             __bf16* __restrict__ qb,
                                             __bf16* __restrict__ kt,
                                             __bf16* __restrict__ vt) {
  __shared__ __bf16 XN[64][264];
  int w = threadIdx.x >> 6, l = threadIdx.x & 63, lr = l & 15, lg = l >> 4;
  int m0 = blockIdx.x * 64;
  int n0 = blockIdx.y * 64;
  // ---- LN: wave w handles rows w*16..+16 (64 lanes x 4 cols each)
  {
    f32x4 lwv = *reinterpret_cast<const f32x4*>(&lw[4 * l]);
    f32x4 lbv = *reinterpret_cast<const f32x4*>(&lb[4 * l]);
    #pragma unroll 4
    for (int rr = 0; rr < 16; ++rr) {
      int row = w * 16 + rr;
      f32x4 v = *reinterpret_cast<const f32x4*>(&x[(size_t)(m0 + row) * DMODEL + 4 * l]);
      float s = v[0] + v[1] + v[2] + v[3];
      #pragma unroll
      for (int off = 32; off >= 1; off >>= 1) s += __shfl_xor(s, off);
      float mean = s * (1.0f / DMODEL);
      float sq = 0.f;
      f32x4 c;
      #pragma unroll
      for (int j = 0; j < 4; ++j) { c[j] = v[j] - mean; sq += c[j] * c[j]; }
      #pragma unroll
      for (int off = 32; off >= 1; off >>= 1) sq += __shfl_xor(sq, off);
      float rstd = rsqrtf(sq * (1.0f / DMODEL) + 1e-5f);
      bf16x4 o4;
      #pragma unroll
      for (int j = 0; j < 4; ++j) o4[j] = (__bf16)(c[j] * rstd * lwv[j] + lbv[j]);
      *reinterpret_cast<bf16x4*>(&XN[row][4 * l]) = o4;
    }
  }
  __syncthreads();
  // ---- GEMM: wave w rows w*16..+16, A from LDS
  f32x4 acc[4] = {};
  const __bf16* bp = Bt + (size_t)(n0 + lr) * DMODEL + 8 * lg;
  for (int kc = 0; kc < DMODEL; kc += 32) {
    bf16x8 a = *reinterpret_cast<const bf16x8*>(&XN[w * 16 + lr][kc + 8 * lg]);
    #pragma unroll
    for (int t = 0; t < 4; ++t) {
      bf16x8 b = ldg8(bp + (size_t)t * 16 * DMODEL + kc);
      acc[t] = MFMA16(a, b, acc[t]);
    }
  }
  int row = m0 + w * 16 + lg * 4;
  if (n0 < DMODEL) {
    #pragma unroll
    for (int t = 0; t < 4; ++t) {
      int col = n0 + t * 16 + lr;
      #pragma unroll
      for (int r = 0; r < 4; ++r)
        qb[(size_t)(row + r) * DMODEL + col] = (__bf16)(acc[t][r] * QSCALE);
    }
  } else if (n0 < 2 * DMODEL) {
    int b_ = row >> 10, s = row & (SEQ - 1);
    #pragma unroll
    for (int t = 0; t < 4; ++t) {
      int hdh = n0 - DMODEL + t * 16 + lr;
      int h = hdh >> 5, dh = hdh & 31;
      size_t base = ((size_t)(b_ * NHEAD + h) * SEQ + s) * DHEAD + dh;
      #pragma unroll
      for (int r = 0; r < 4; ++r) kt[base + (size_t)r * DHEAD] = (__bf16)acc[t][r];
    }
  } else {
    int b_ = row >> 10, s = row & (SEQ - 1);
    #pragma unroll
    for (int t = 0; t < 4; ++t) {
      int hdh = n0 - 2 * DMODEL + t * 16 + lr;
      int h = hdh >> 5, dh = hdh & 31;
      bf16x4 v4;
      #pragma unroll
      for (int r = 0; r < 4; ++r) v4[r] = (__bf16)acc[t][r];
      *reinterpret_cast<bf16x4*>(vt + ((size_t)(b_ * NHEAD + h) * DHEAD + dh) * SEQ + s) = v4;
    }
  }
}

// ---------------- attention, two-pass, K-split across 8 waves, XCD-swizzled --------
// (R16 version: staged aw tile in LDS, NON-TEMPORAL coalesced dwordx4 flush)
__global__ __launch_bounds__(512, 6) void k_attn(const __bf16* __restrict__ qb,
                                                 const __bf16* __restrict__ kt,
                                                 const __bf16* __restrict__ vt,
                                                 __bf16* __restrict__ ob,
                                                 float* __restrict__ aw) {
  __shared__ __bf16 P[8][2][16][40];
  __shared__ float  Ssum[8][16];
  __shared__ float  OS[8][16][34];       // end: O partials; during pass B: aliased as ST staging
  int bid = blockIdx.x;
  int swz = (bid & 7) * 256 + (bid >> 3);      // 2048 = 8 XCD chunks of 256
  int qblk = swz & 63, h = (swz >> 6) & 7, b = swz >> 9;
  int w = threadIdx.x >> 6, l = threadIdx.x & 63, lr = l & 15, lg = l >> 4;
  int q0 = qblk * 16;
  bf16x8 qf = ldg8(qb + ((size_t)(b * SEQ) + q0 + lr) * DMODEL + h * DHEAD + 8 * lg);
  const __bf16* ktb = kt + (size_t)(b * NHEAD + h) * SEQ * DHEAD + 8 * lg;
  const __bf16* vtb = vt + (size_t)(b * NHEAD + h) * DHEAD * SEQ;
  f32x4 z = {};
  int kbeg = w * 128;

  // ---- pass A: partial row sums of exp2(d) over this wave's 128 keys
  float s4[4] = {0.f, 0.f, 0.f, 0.f};
  #pragma unroll 4
  for (int t = 0; t < 8; ++t) {
    bf16x8 kf = ldg8(ktb + (size_t)(kbeg + t * 16 + lr) * DHEAD);
    f32x4 d = MFMA16(qf, kf, z);
    #pragma unroll
    for (int r = 0; r < 4; ++r) s4[r] += exp2f(d[r]);
  }
  #pragma unroll
  for (int off = 1; off < 16; off <<= 1) {
    #pragma unroll
    for (int r = 0; r < 4; ++r) s4[r] += __shfl_xor(s4[r], off);
  }
  if (lr == 0) {
    #pragma unroll
    for (int r = 0; r < 4; ++r) Ssum[w][lg * 4 + r] = s4[r];
  }
  __syncthreads();
  float rinv[4];
  #pragma unroll
  for (int r = 0; r < 4; ++r) {
    int row = lg * 4 + r;
    float s = Ssum[0][row] + Ssum[1][row] + Ssum[2][row] + Ssum[3][row]
            + Ssum[4][row] + Ssum[5][row] + Ssum[6][row] + Ssum[7][row];
    rinv[r] = 1.0f / s;
  }

  // ---- pass B: recompute, stage normalized fp32 tile in LDS, nt coalesced flush
  float* awb = aw + ((size_t)(b * NHEAD + h) * SEQ) * SEQ;
  float (*ST)[32] = reinterpret_cast<float(*)[32]>(&OS[w][0][0]);   // per-wave 16x32 staging

#define QK_TILE(KC, BUF)                                                          \
  {                                                                               \
    _Pragma("unroll")                                                             \
    for (int half = 0; half < 2; ++half) {                                        \
      int k0 = (KC) + half * 16;                                                  \
      bf16x8 kf = ldg8(ktb + (size_t)(k0 + lr) * DHEAD);                          \
      f32x4 d = MFMA16(qf, kf, z);                                                \
      _Pragma("unroll")                                                           \
      for (int r = 0; r < 4; ++r) {                                               \
        float pn = exp2f(d[r]) * rinv[r];                                         \
        ST[lg * 4 + r][half * 16 + lr] = pn;                                      \
        P[w][BUF][lg * 4 + r][half * 16 + lr] = (__bf16)pn;                       \
      }                                                                           \
    }                                                                             \
  }

#define FLUSH(KC)                                                                 \
  {                                                                               \
    int frow = l >> 3, fcol = (l & 7) * 4;                                        \
    f32x4 v0 = *reinterpret_cast<const f32x4*>(&ST[frow][fcol]);                  \
    f32x4 v1 = *reinterpret_cast<const f32x4*>(&ST[frow + 8][fcol]);              \
    __builtin_nontemporal_store(v0, reinterpret_cast<f32x4*>(                     \
        &awb[(size_t)(q0 + frow) * SEQ + (KC) + fcol]));                          \
    __builtin_nontemporal_store(v1, reinterpret_cast<f32x4*>(                     \
        &awb[(size_t)(q0 + frow + 8) * SEQ + (KC) + fcol]));                      \
  }

  f32x4 accO[2] = {};
  QK_TILE(kbeg, 0)
  #pragma unroll
  for (int j = 1; j < 4; ++j) {
    int kc = kbeg + j * 32;
    bf16x8 pf  = *reinterpret_cast<const bf16x8*>(&P[w][(j - 1) & 1][lr][8 * lg]);
    bf16x8 vf0 = ldg8(vtb + (size_t)lr * SEQ + (kc - 32) + 8 * lg);
    bf16x8 vf1 = ldg8(vtb + (size_t)(16 + lr) * SEQ + (kc - 32) + 8 * lg);
    FLUSH(kc - 32)
    QK_TILE(kc, j & 1)
    accO[0] = MFMA16(pf, vf0, accO[0]);
    accO[1] = MFMA16(pf, vf1, accO[1]);
  }
  {                                      // last chunk (j=3 -> buf 1)
    bf16x8 pf  = *reinterpret_cast<const bf16x8*>(&P[w][1][lr][8 * lg]);
    bf16x8 vf0 = ldg8(vtb + (size_t)lr * SEQ + (kbeg + 96) + 8 * lg);
    bf16x8 vf1 = ldg8(vtb + (size_t)(16 + lr) * SEQ + (kbeg + 96) + 8 * lg);
    FLUSH(kbeg + 96)
    accO[0] = MFMA16(pf, vf0, accO[0]);
    accO[1] = MFMA16(pf, vf1, accO[1]);
  }
#undef QK_TILE
#undef FLUSH

  // O partials (P was normalized -> no rinv here), then cross-wave reduction
  #pragma unroll
  for (int t = 0; t < 2; ++t)
    #pragma unroll
    for (int r = 0; r < 4; ++r) OS[w][lg * 4 + r][t * 16 + lr] = accO[t][r];
  __syncthreads();
  int row = threadIdx.x >> 5, col = threadIdx.x & 31;   // 512 thr = 16 rows x 32 cols
  float o = 0.f;
  #pragma unroll
  for (int ww = 0; ww < 8; ++ww) o += OS[ww][row][col];
  ob[((size_t)(b * SEQ) + q0 + row) * DMODEL + h * DHEAD + col] = (__bf16)o;
}

// ------ fused: out-proj + residual + LN2 + FFN1 + in-wave GEGLU + FFN2 + residual
//        + LN1(next) + QKV(next) -- 512 threads, 16 rows/block (R16 version) ------
template <int LAST>
__global__ __launch_bounds__(512) void k_pf(const __bf16* __restrict__ ob,
                                            const __bf16* __restrict__ woutT,
                                            const float* __restrict__ xres,
                                            const float* __restrict__ ln2w,
                                            const float* __restrict__ ln2b,
                                            const __bf16* __restrict__ w1t,
                                            const float* __restrict__ b1,
                                            const __bf16* __restrict__ w2t,
                                            const float* __restrict__ b2,
                                            float* __restrict__ x32out,
                                            const float* __restrict__ lnw_n,
                                            const float* __restrict__ lnb_n,
                                            const __bf16* __restrict__ wqkvT_n,
                                            __bf16* __restrict__ qb,
                                            __bf16* __restrict__ kt,
                                            __bf16* __restrict__ vt,
                                            float* __restrict__ xout) {
  __shared__ float  xs[16][268];
  __shared__ __bf16 XN[16][264];
  __shared__ __bf16 HT[16][136];
  int w = threadIdx.x >> 6, l = threadIdx.x & 63, lr = l & 15, lg = l >> 4;
  int m0 = blockIdx.x * 16;
  // ---- out-proj GEMM, wave w -> 32 cols
  {
    int n0 = w * 32;
    f32x4 acc[2] = {};
    const __bf16* ap = ob + (size_t)(m0 + lr) * DMODEL + 8 * lg;
    const __bf16* bp = woutT + (size_t)(n0 + lr) * DMODEL + 8 * lg;
    for (int kc = 0; kc < DMODEL; kc += 32) {
      bf16x8 a = ldg8(ap + kc);
      #pragma unroll
      for (int t = 0; t < 2; ++t)
        acc[t] = MFMA16(a, ldg8(bp + (size_t)t * 16 * DMODEL + kc), acc[t]);
    }
    #pragma unroll
    for (int t = 0; t < 2; ++t) {
      int col = n0 + t * 16 + lr;
      #pragma unroll
      for (int r = 0; r < 4; ++r) {
        int row = lg * 4 + r;
        xs[row][col] = acc[t][r] + xres[(size_t)(m0 + row) * DMODEL + col];
      }
    }
  }
  __syncthreads();
  // ---- LN2 -> XN (LDS); wave w handles rows w*2..+2
  #pragma unroll
  for (int rr = 0; rr < 2; ++rr) {
    int row = w * 2 + rr;
    f32x4 v = *reinterpret_cast<const f32x4*>(&xs[row][4 * l]);
    float s = v[0] + v[1] + v[2] + v[3];
    #pragma unroll
    for (int off = 32; off >= 1; off >>= 1) s += __shfl_xor(s, off);
    float mean = s * (1.0f / DMODEL);
    float sq = 0.f;
    f32x4 c;
    #pragma unroll
    for (int j = 0; j < 4; ++j) { c[j] = v[j] - mean; sq += c[j] * c[j]; }
    #pragma unroll
    for (int off = 32; off >= 1; off >>= 1) sq += __shfl_xor(sq, off);
    float rstd = rsqrtf(sq * (1.0f / DMODEL) + 1e-5f);
    f32x4 lwv = *reinterpret_cast<const f32x4*>(&ln2w[4 * l]);
    f32x4 lbv = *reinterpret_cast<const f32x4*>(&ln2b[4 * l]);
    bf16x4 o4;
    #pragma unroll
    for (int j = 0; j < 4; ++j) o4[j] = (__bf16)(c[j] * rstd * lwv[j] + lbv[j]);
    *reinterpret_cast<bf16x4*>(&XN[row][4 * l]) = o4;
  }
  __syncthreads();
  // ---- FFN1: wave w -> a-cols [w*16,+16) and g-cols [128+w*16,+16); in-wave GEGLU
  {
    f32x4 acc1[2] = {};
    const __bf16* bpa = w1t + (size_t)(w * 16 + lr) * DMODEL + 8 * lg;
    const __bf16* bpg = w1t + (size_t)(128 + w * 16 + lr) * DMODEL + 8 * lg;
    for (int kc = 0; kc < DMODEL; kc += 32) {
      bf16x8 a = *reinterpret_cast<const bf16x8*>(&XN[lr][kc + 8 * lg]);
      acc1[0] = MFMA16(a, ldg8(bpa + kc), acc1[0]);
      acc1[1] = MFMA16(a, ldg8(bpg + kc), acc1[1]);
    }
    int fc = w * 16 + lr;
    #pragma unroll
    for (int r = 0; r < 4; ++r) {
      float a1 = acc1[0][r] + b1[fc];
      float g  = acc1[1][r] + b1[fc + 128];
      float ge = 0.5f * g * (1.0f + erff(g * 0.70710678118654752f));
      HT[lg * 4 + r][fc] = (__bf16)(a1 * ge);
    }
  }
  __syncthreads();
  // ---- FFN2: wave w -> 32 cols, K = 128
  {
    int n0 = w * 32;
    f32x4 acc2[2] = {};
    const __bf16* bp = w2t + (size_t)(n0 + lr) * FFDIM + 8 * lg;
    for (int kc = 0; kc < FFDIM; kc += 32) {
      bf16x8 a2 = *reinterpret_cast<const bf16x8*>(&HT[lr][kc + 8 * lg]);
      #pragma unroll
      for (int t = 0; t < 2; ++t)
        acc2[t] = MFMA16(a2, ldg8(bp + (size_t)t * 16 * FFDIM + kc), acc2[t]);
    }
    #pragma unroll
    for (int t = 0; t < 2; ++t) {
      int col = n0 + t * 16 + lr;
      #pragma unroll
      for (int r = 0; r < 4; ++r) {
        int row = lg * 4 + r;
        xs[row][col] = acc2[t][r] + b2[col] + xs[row][col];
      }
    }
  }
  __syncthreads();
  // ---- final: residual out + LN1(next) -> XN (LDS), or fp32 output
  #pragma unroll
  for (int rr = 0; rr < 2; ++rr) {
    int row = w * 2 + rr;
    f32x4 v = *reinterpret_cast<const f32x4*>(&xs[row][4 * l]);
    if (LAST) {
      *reinterpret_cast<f32x4*>(&xout[(size_t)(m0 + row) * DMODEL + 4 * l]) = v;
    } else {
      float s = v[0] + v[1] + v[2] + v[3];
      #pragma unroll
      for (int off = 32; off >= 1; off >>= 1) s += __shfl_xor(s, off);
      float mean = s * (1.0f / DMODEL);
      float sq = 0.f;
      f32x4 c;
      #pragma unroll
      for (int j = 0; j < 4; ++j) { c[j] = v[j] - mean; sq += c[j] * c[j]; }
      #pragma unroll
      for (int off = 32; off >= 1; off >>= 1) sq += __shfl_xor(sq, off);
      float rstd = rsqrtf(sq * (1.0f / DMODEL) + 1e-5f);
      *reinterpret_cast<f32x4*>(&x32out[(size_t)(m0 + row) * DMODEL + 4 * l]) = v;
      f32x4 lwv = *reinterpret_cast<const f32x4*>(&lnw_n[4 * l]);
      f32x4 lbv = *reinterpret_cast<const f32x4*>(&lnb_n[4 * l]);
      bf16x4 o4;
      #pragma unroll
      for (int j = 0; j < 4; ++j) o4[j] = (__bf16)(c[j] * rstd * lwv[j] + lbv[j]);
      *reinterpret_cast<bf16x4*>(&XN[row][4 * l]) = o4;
    }
  }
  if (!LAST) {
    __syncthreads();
    // ---- QKV(next): wave w -> 96 cols of 768; A = XN (LDS)
    f32x4 acc[6] = {};
    {
      const __bf16* bp = wqkvT_n + (size_t)(w * 96 + lr) * DMODEL + 8 * lg;
      for (int kc = 0; kc < DMODEL; kc += 32) {
        bf16x8 a = *reinterpret_cast<const bf16x8*>(&XN[lr][kc + 8 * lg]);
        #pragma unroll
        for (int t = 0; t < 6; ++t)
          acc[t] = MFMA16(a, ldg8(bp + (size_t)t * 16 * DMODEL + kc), acc[t]);
      }
    }
    int row = m0 + lg * 4;
    int b_ = row >> 10, s = row & (SEQ - 1);
    #pragma unroll
    for (int t = 0; t < 6; ++t) {
      int col = w * 96 + t * 16 + lr;    // tile col range is 16-aligned -> uniform branch
      if (col < DMODEL) {                // Q (prescaled)
        #pragma unroll
        for (int r = 0; r < 4; ++r)
          qb[(size_t)(row + r) * DMODEL + col] = (__bf16)(acc[t][r] * QSCALE);
      } else if (col < 2 * DMODEL) {     // K -> kt[((b*8+h)*1024+s)*32+dh]
        int hdh = col - DMODEL;
        int h = hdh >> 5, dh = hdh & 31;
        size_t base = ((size_t)(b_ * NHEAD + h) * SEQ + s) * DHEAD + dh;
        #pragma unroll
        for (int r = 0; r < 4; ++r) kt[base + (size_t)r * DHEAD] = (__bf16)acc[t][r];
      } else {                           // V -> vt[((b*8+h)*32+dh)*1024+s]
        int hdh = col - 2 * DMODEL;
        int h = hdh >> 5, dh = hdh & 31;
        bf16x4 v4;
        #pragma unroll
        for (int r = 0; r < 4; ++r) v4[r] = (__bf16)acc[t][r];
        *reinterpret_cast<bf16x4*>(vt + ((size_t)(b_ * NHEAD + h) * DHEAD + dh) * SEQ + s) = v4;
      }
    }
  }
}

// ---------------- host ----------------
static inline size_t align256(size_t x) { return (x + 255) & ~(size_t)255; }

extern "C" void kernel_launch(void* const* d_in, const int* in_sizes, int n_in,
                              void* d_out, int out_size, void* d_ws, size_t ws_size,
                              hipStream_t stream) {
  const float* x_in = (const float*)d_in[0];
  const float* ln1w = (const float*)d_in[1];
  const float* ln1b = (const float*)d_in[2];
  const float* wqkv = (const float*)d_in[3];
  const float* wout = (const float*)d_in[4];
  const float* ln2w = (const float*)d_in[5];
  const float* ln2b = (const float*)d_in[6];
  const float* w1   = (const float*)d_in[7];
  const float* b1   = (const float*)d_in[8];
  const float* w2   = (const float*)d_in[9];
  const float* b2   = (const float*)d_in[10];
  float* out = (float*)d_out;

  char* p = (char*)d_ws;
  float*  x32   = (float*)p;  p += align256((size_t)ROWS * DMODEL * 4);
  __bf16* qb    = (__bf16*)p; p += align256((size_t)ROWS * DMODEL * 2);
  __bf16* kt    = (__bf16*)p; p += align256((size_t)ROWS * DMODEL * 2);
  __bf16* vt    = (__bf16*)p; p += align256((size_t)ROWS * DMODEL * 2);
  __bf16* ob    = (__bf16*)p; p += align256((size_t)ROWS * DMODEL * 2);
  __bf16* wqkvT = (__bf16*)p; p += align256((size_t)LAYERS * DMODEL * QKVN * 2);
  __bf16* woutT = (__bf16*)p; p += align256((size_t)LAYERS * DMODEL * DMODEL * 2);
  __bf16* w1T   = (__bf16*)p; p += align256((size_t)LAYERS * DMODEL * 2 * FFDIM * 2);
  __bf16* w2T   = (__bf16*)p; p += align256((size_t)LAYERS * FFDIM * DMODEL * 2);

  k_prepAll<<<dim3(88, 1, LAYERS), 256, 0, stream>>>(wqkv, wout, w1, w2,
                                                     wqkvT, woutT, w1T, w2T);
  k_qkv<<<dim3(ROWS / 64, QKVN / 64), 256, 0, stream>>>(x_in, ln1w, ln1b, wqkvT, qb, kt, vt);

  const size_t AW_LAYER = (size_t)BATCH * NHEAD * SEQ * SEQ;
  for (int i = 0; i < LAYERS; ++i) {
    float* aw_l = out + (size_t)ROWS * DMODEL + (size_t)i * AW_LAYER;
    k_attn<<<SEQ / 16 * NHEAD * BATCH, 512, 0, stream>>>(qb, kt, vt, ob, aw_l);
    const float* xres = (i == 0) ? x_in : x32;
    if (i < LAYERS - 1) {
      k_pf<0><<<ROWS / 16, 512, 0, stream>>>(
          ob, woutT + (size_t)i * DMODEL * DMODEL, xres,
          ln2w + i * DMODEL, ln2b + i * DMODEL,
          w1T + (size_t)i * DMODEL * 2 * FFDIM, b1 + i * 2 * FFDIM,
          w2T + (size_t)i * FFDIM * DMODEL, b2 + i * DMODEL,
          x32, ln1w + (i + 1) * DMODEL, ln1b + (i + 1) * DMODEL,
          wqkvT + (size_t)(i + 1) * DMODEL * QKVN, qb, kt, vt, nullptr);
    } else {
      k_pf<1><<<ROWS / 16, 512, 0, stream>>>(
          ob, woutT + (size_t)i * DMODEL * DMODEL, xres,
          ln2w + i * DMODEL, ln2b + i * DMODEL,
          w1T + (size_t)i * DMODEL * 2 * FFDIM, b1 + i * 2 * FFDIM,
          w2T + (size_t)i * FFDIM * DMODEL, b2 + i * DMODEL,
          x32, nullptr, nullptr, nullptr, nullptr, nullptr, nullptr, out);
    }
  }
}